// Round 18
// baseline (537.857 us; speedup 1.0000x reference)
//
#include <hip/hip_runtime.h>
#include <math.h>

#define DIM  1024   // hidden dim D
#define NEXP 8      // experts
#define HID  4096   // expert hidden H
#define TOPK 2

typedef __attribute__((ext_vector_type(8))) short bf16x8;
typedef __attribute__((ext_vector_type(4))) float f32x4;

__device__ inline unsigned short f2bf(float f) {
  union { float f; unsigned int u; } v; v.f = f;
  unsigned int u = v.u;
  return (unsigned short)((u + 0x7FFFu + ((u >> 16) & 1u)) >> 16);
}

__device__ inline void load_lds16(const void* g, void* l) {
  __builtin_amdgcn_global_load_lds(
      (const __attribute__((address_space(1))) void*)g,
      (__attribute__((address_space(3))) void*)l, 16, 0, 0);
}

// exact-enough gelu: Abramowitz-Stegun 7.1.26 erf, |err| <= 1.5e-7 (<< bf16 rounding)
__device__ inline float gelu_f(float v) {
  float x = v * 0.70710678118654752f;
  float ax = fabsf(x);
  float t = 1.f / (1.f + 0.3275911f * ax);
  float poly = t * (0.254829592f + t * (-0.284496736f + t * (1.421413741f +
               t * (-1.453152027f + t * 1.061405429f))));
  float er = 1.f - poly * __expf(-ax * ax);
  er = (x < 0.f) ? -er : er;
  return 0.5f * v * (1.f + er);
}

// ---------------- gate: logits -> softmax -> top2 -> routing lists ----------------
__global__ void gate_kernel(const float* __restrict__ x,
                            const float* __restrict__ Wg,
                            const float* __restrict__ bg,
                            float* __restrict__ topk_score,
                            int* __restrict__ count,
                            int* __restrict__ lists,
                            int N) {
  int n = blockIdx.x;
  if (n >= N) return;
  int lane = threadIdx.x;
  float acc[NEXP];
#pragma unroll
  for (int e = 0; e < NEXP; ++e) acc[e] = 0.f;
  const float* xr = x + (size_t)n * DIM;
  for (int d = lane; d < DIM; d += 64) {
    float xv = xr[d];
    const float* w = Wg + (size_t)d * NEXP;
#pragma unroll
    for (int e = 0; e < NEXP; ++e) acc[e] += xv * w[e];
  }
#pragma unroll
  for (int off = 32; off > 0; off >>= 1) {
#pragma unroll
    for (int e = 0; e < NEXP; ++e) acc[e] += __shfl_xor(acc[e], off, 64);
  }
  if (lane == 0) {
    float l[NEXP];
#pragma unroll
    for (int e = 0; e < NEXP; ++e) l[e] = acc[e] + bg[e];
    float m = l[0];
#pragma unroll
    for (int e = 1; e < NEXP; ++e) m = fmaxf(m, l[e]);
    float p[NEXP];
    float s = 0.f;
#pragma unroll
    for (int e = 0; e < NEXP; ++e) { p[e] = expf(l[e] - m); s += p[e]; }
    int i0 = 0;
#pragma unroll
    for (int e = 1; e < NEXP; ++e) if (l[e] > l[i0]) i0 = e;
    int i1 = (i0 == 0) ? 1 : 0;
#pragma unroll
    for (int e = 0; e < NEXP; ++e) if (e != i0 && l[e] > l[i1]) i1 = e;
    float inv = 1.f / s;
    topk_score[n * TOPK + 0] = p[i0] * inv;
    topk_score[n * TOPK + 1] = p[i1] * inv;
    int pos0 = atomicAdd(&count[i0], 1);
    lists[(size_t)i0 * N + pos0] = n * TOPK + 0;
    int pos1 = atomicAdd(&count[i1], 1);
    lists[(size_t)i1 * N + pos1] = n * TOPK + 1;
  }
}

// offsets + flattened 256-row tile table (kills dead blocks)
__global__ void offsets_kernel(const int* __restrict__ count, int* __restrict__ offsets,
                               int* __restrict__ tiles, int* __restrict__ ntiles) {
  if (threadIdx.x == 0 && blockIdx.x == 0) {
    int s = 0, nt = 0;
    for (int e = 0; e < NEXP; ++e) {
      offsets[e] = s;
      int c = count[e];
      s += c;
      int rts = (c + 255) >> 8;
      for (int i = 0; i < rts; ++i) tiles[nt++] = (e << 16) | i;
    }
    offsets[NEXP] = s;
    ntiles[0] = nt;
  }
}

// gather token rows (sorted by expert) into bf16 Xg; record pair mapping
// TILED=1: Xg layout [kb=DIM/64][NPAD][64] (K-tiled, contiguous staging blocks)
template <int TILED>
__global__ void gather_kernel(const float* __restrict__ x,
                              const int* __restrict__ offsets,
                              const int* __restrict__ lists,
                              unsigned short* __restrict__ Xg,
                              int* __restrict__ pairmap,
                              int N, int NPAD) {
  int g = blockIdx.x;
  int e = 0;
  while (e < NEXP - 1 && g >= offsets[e + 1]) ++e;
  int i = g - offsets[e];
  int ent = lists[(size_t)e * N + i];
  int tok = ent >> 1;
  if (threadIdx.x == 0) pairmap[g] = ent;
  int d0 = threadIdx.x * 4;
  float4 v = *((const float4*)(x + (size_t)tok * DIM + d0));
  ushort4 o;
  o.x = f2bf(v.x); o.y = f2bf(v.y); o.z = f2bf(v.z); o.w = f2bf(v.w);
  if (TILED) {
    *(ushort4*)(Xg + ((size_t)(d0 >> 6) * NPAD + g) * 64 + (d0 & 63)) = o;
  } else {
    *(ushort4*)(Xg + (size_t)g * DIM + d0) = o;
  }
}

// --- merged transpose-convert: W1 [e][1024][4096] and W2 [e][4096][1024] fp32
//     -> W1T/W2T [e][R/64][C][64] bf16 (K-tiled). One launch (r16: -11 us).
__global__ __launch_bounds__(256) void transpose_convert_all(
    const float* __restrict__ W1, const float* __restrict__ W2,
    unsigned short* __restrict__ W1T, unsigned short* __restrict__ W2T) {
  int idx = blockIdx.x;
  const float* src; unsigned short* dst; int C, r0, c0base;
  if (idx < 2048) {            // W1: 8 experts x (1024/64 rt) x (4096/256 ct4)
    const int e = idx >> 8, rem = idx & 255;
    C = 4096;
    r0 = (rem >> 4) * 64;
    c0base = (rem & 15) * 256;
    src = W1 + (size_t)e * 1024 * 4096;
    dst = W1T + (size_t)e * 1024 * 4096;
  } else {                     // W2: 8 experts x (4096/64 rt) x (1024/256 ct4)
    idx -= 2048;
    const int e = idx >> 8, rem = idx & 255;
    C = 1024;
    r0 = (rem >> 2) * 64;
    c0base = (rem & 3) * 256;
    src = W2 + (size_t)e * 4096 * 1024;
    dst = W2T + (size_t)e * 4096 * 1024;
  }
  __shared__ unsigned short Ts[64][68];
  const int t = threadIdx.x;
  const int rr = t >> 4, cc = (t & 15) * 4;
  const int cr = t >> 3, rq = (t & 7) * 8;
  const size_t kbbase = (size_t)(r0 >> 6) * C;
  for (int sub = 0; sub < 4; ++sub) {
    const int c0 = c0base + sub * 64;
#pragma unroll
    for (int p = 0; p < 4; ++p) {
      int r = rr + p * 16;
      float4 v = *(const float4*)(src + (size_t)(r0 + r) * C + c0 + cc);
      Ts[cc + 0][r] = f2bf(v.x);
      Ts[cc + 1][r] = f2bf(v.y);
      Ts[cc + 2][r] = f2bf(v.z);
      Ts[cc + 3][r] = f2bf(v.w);
    }
    __syncthreads();
#pragma unroll
    for (int p = 0; p < 2; ++p) {
      int c = cr + p * 32;
      ushort4 a = *(ushort4*)&Ts[c][rq];
      ushort4 b = *(ushort4*)&Ts[c][rq + 4];
      unsigned short* dp = dst + (kbbase + (c0 + c)) * 64 + rq;
      *(ushort4*)(dp) = a;
      *(ushort4*)(dp + 4) = b;
    }
    __syncthreads();
  }
}

// ---- grouped bf16 GEMM: 256x128 tile, 512 thr (8 waves, 4x2, wave-tile 64x64),
// BK=32, SINGLE-buffered 24 KB LDS. Staged-byte demand 17% below the 128x128 tile
// (model: passes run at the ~6 TB/s per-CU VMEM-path ceiling; time = bytes/rate)
// while VGPR ~56-64 (r14-measured for this body) keeps 8 waves/SIMD legal and LDS
// allows >=4 blocks/CU -> r15's occupancy regime preserved. Same drain-barrier loop.
// Linear LDS, linear lane-contiguous global_load_lds from K-tiled operands.
// 1D grid, tile-fastest, bijective chunked XCD swizzle.
// PASS 1: Hmat_t = gelu(Xg_t * W1T^T + b1)   (K-tiled output for pass-2 staging)
// PASS 2 (kz=0,1): out[tok] += score * (Hmat_kslice * W2T_kslice^T [+ b2 if kz==0])
template <int PASS>
__global__ __launch_bounds__(512) void moe_gemm16(
    const unsigned short* __restrict__ Asrc,
    const unsigned short* __restrict__ Bt,
    const float* __restrict__ bias,
    const int* __restrict__ offsets,
    const int* __restrict__ tiles,
    const int* __restrict__ ntiles,
    const int* __restrict__ pairmap,
    const float* __restrict__ score,
    unsigned short* __restrict__ Hmat,
    float* __restrict__ out,
    int maxt, int NPAD) {
  constexpr int K  = (PASS == 1) ? DIM : HID;   // reduction dim
  constexpr int NS = (PASS == 1) ? HID : DIM;   // output width
  constexpr int KS = (PASS == 1) ? 1 : 2;       // k-split (pass2: 2x blocks)
  constexpr int KL = K / KS;
  constexpr int NT = KL / 32;                   // K-steps (32 or 64)
  constexpr int KBK = K / 64;                   // 64-elem k-blocks in operands

  // bijective chunked XCD swizzle (m204)
  const unsigned orig = blockIdx.x;
  const unsigned nwg = gridDim.x;
  const unsigned q = nwg >> 3, r8 = nwg & 7;
  const unsigned xcd = orig & 7, p8 = orig >> 3;
  const unsigned id = (xcd < r8 ? xcd * (q + 1) : r8 * (q + 1) + (xcd - r8) * q) + p8;
  const int tt = (int)(id % (unsigned)maxt);    // row-tile (fastest)
  const int ct = (int)(id / (unsigned)maxt);    // column tile (128 wide)

  if (tt >= ntiles[0]) return;
  const int pk = tiles[tt];
  const int e  = pk >> 16;
  const int rt = pk & 0xffff;
  const int gbase = offsets[e];
  const int nc = offsets[e + 1] - gbase;
  const int rowsvalid = min(256, nc - rt * 256);
  const int kz = (PASS == 1) ? 0 : blockIdx.z;
  const int kb0 = (kz * KL) >> 6;               // first 64-elem k-block of this slice

  __shared__ unsigned short As[256 * 32];   // 16 KB
  __shared__ unsigned short Bs[128 * 32];   //  8 KB  -> 24 KB total

  const int tid  = threadIdx.x;
  const int lane = tid & 63;
  const int wid  = tid >> 6;        // 0..7
  const int wr = (wid >> 1) * 64;   // wave row base: 0,64,128,192
  const int wc = (wid & 1) * 64;    // wave col base: 0,64
  const int fr = lane & 15;
  const int fq = lane >> 4;

  f32x4 acc[4][4];
#pragma unroll
  for (int m = 0; m < 4; ++m)
#pragma unroll
    for (int n = 0; n < 4; ++n) acc[m][n] = (f32x4){0.f, 0.f, 0.f, 0.f};

  // K-tiled bases; step t reads half-slab: kb = kb0 + (t>>1), k-half = t&1
  const unsigned short* Ab = Asrc + ((size_t)kb0 * NPAD + (gbase + rt * 256)) * 64;
  const unsigned short* Bb = Bt + (((size_t)e * KBK + kb0) * NS + (size_t)ct * 128) * 64;

  for (int t = 0; t < NT; ++t) {
    // stage tile t: A 1024 units (2/thread) + B 512 units (1/thread)
    {
      const unsigned short* ga = Ab + (size_t)(t >> 1) * ((size_t)NPAD * 64) + (t & 1) * 32;
      const unsigned short* gb = Bb + (size_t)(t >> 1) * ((size_t)NS * 64) + (t & 1) * 32;
#pragma unroll
      for (int i = 0; i < 2; ++i) {
        const int c = i * 512 + tid;            // A 16B-unit index, 0..1023
        const int row = c >> 2;
        const int u = c & 3;
        load_lds16(ga + (size_t)row * 64 + u * 8, (char*)As + c * 16);
      }
      {
        const int c = tid;                      // B 16B-unit index, 0..511
        const int row = c >> 2;
        const int u = c & 3;
        load_lds16(gb + (size_t)row * 64 + u * 8, (char*)Bs + c * 16);
      }
    }
    __syncthreads();   // compiler drains vmcnt(0): tile t resident in LDS

    {
      bf16x8 af[4], bf[4];
#pragma unroll
      for (int m = 0; m < 4; ++m)
        af[m] = *(const bf16x8*)&As[(wr + m * 16 + fr) * 32 + fq * 8];
#pragma unroll
      for (int n = 0; n < 4; ++n)
        bf[n] = *(const bf16x8*)&Bs[(wc + n * 16 + fr) * 32 + fq * 8];
#pragma unroll
      for (int m = 0; m < 4; ++m)
#pragma unroll
        for (int n = 0; n < 4; ++n)
          acc[m][n] = __builtin_amdgcn_mfma_f32_16x16x32_bf16(af[m], bf[n], acc[m][n], 0, 0, 0);
    }
    __syncthreads();   // all waves done reading -> safe to overwrite next iter
  }

  if (PASS == 1) {
    const size_t cb = (size_t)(ct * 2 + (wc >> 6));   // output k-block in Hmat_t
#pragma unroll
    for (int n = 0; n < 4; ++n) {
      const int col = ct * 128 + wc + n * 16 + fr;
      const int cl = n * 16 + fr;                     // col within 64-block
      const float b1v = bias[(size_t)e * NS + col];
#pragma unroll
      for (int m = 0; m < 4; ++m) {
#pragma unroll
        for (int r = 0; r < 4; ++r) {
          const int lrow = wr + m * 16 + fq * 4 + r;
          if (lrow < rowsvalid) {
            float v = gelu_f(acc[m][n][r] + b1v);
            Hmat[(cb * NPAD + (gbase + rt * 256 + lrow)) * 64 + cl] = f2bf(v);
          }
        }
      }
    }
  } else {
    float b2v[4];
#pragma unroll
    for (int n = 0; n < 4; ++n)
      b2v[n] = (kz == 0) ? bias[(size_t)e * NS + ct * 128 + wc + n * 16 + fr] : 0.f;
#pragma unroll
    for (int m = 0; m < 4; ++m) {
#pragma unroll
      for (int r = 0; r < 4; ++r) {
        const int lrow = wr + m * 16 + fq * 4 + r;
        if (lrow < rowsvalid) {
          const int g = gbase + rt * 256 + lrow;
          const int ent = pairmap[g];
          const int tok = ent >> 1;
          const float s = score[ent];
#pragma unroll
          for (int n = 0; n < 4; ++n) {
            const int col = ct * 128 + wc + n * 16 + fr;
            atomicAdd(&out[(size_t)tok * DIM + col], s * (acc[m][n][r] + b2v[n]));
          }
        }
      }
    }
  }
}

// ============== fallback: round-1 GEMM (fp32 weights converted in-loop) ==============
template <int PASS>
__global__ __launch_bounds__(256) void moe_gemm(
    const unsigned short* __restrict__ Asrc,
    const float* __restrict__ Bsrc,
    const float* __restrict__ bias,
    const int* __restrict__ offsets,
    const int* __restrict__ pairmap,
    const float* __restrict__ score,
    unsigned short* __restrict__ Hmat,
    float* __restrict__ out) {
  constexpr int K  = (PASS == 1) ? DIM : HID;
  constexpr int NS = (PASS == 1) ? HID : DIM;
  const int e = blockIdx.z;
  const int gbase = offsets[e];
  const int nc = offsets[e + 1] - gbase;
  const int rt = blockIdx.x;
  if (rt * 128 >= nc) return;
  const int rowsvalid = min(128, nc - rt * 128);
  const int ct = blockIdx.y;
  __shared__ unsigned short As[128 * 40];
  __shared__ unsigned short Bs[128 * 40];
  const int tid  = threadIdx.x;
  const int lane = tid & 63;
  const int wid  = tid >> 6;
  const int wr = (wid >> 1) * 64;
  const int wc = (wid & 1) * 64;
  const int fr = lane & 15;
  const int fq = lane >> 4;
  f32x4 acc[4][4];
#pragma unroll
  for (int m = 0; m < 4; ++m)
#pragma unroll
    for (int n = 0; n < 4; ++n) acc[m][n] = (f32x4){0.f, 0.f, 0.f, 0.f};
  const int ar = tid >> 1;
  const int ak = (tid & 1) * 16;
  int arow = rt * 128 + ((ar < rowsvalid) ? ar : 0);
  const unsigned short* Aptr = Asrc + (size_t)(gbase + arow) * K + ak;
  const int bc = (tid & 31) * 4;
  const int bk = (tid >> 5) * 4;
  const float* Bptr = Bsrc + (size_t)e * K * NS + (size_t)bk * NS + ct * 128 + bc;
  for (int k0 = 0; k0 < K; k0 += 32) {
    uint4 av0 = *(const uint4*)(Aptr + k0);
    uint4 av1 = *(const uint4*)(Aptr + k0 + 8);
    const float* bp = Bptr + (size_t)k0 * NS;
    float4 w0 = *(const float4*)(bp);
    float4 w1 = *(const float4*)(bp + NS);
    float4 w2 = *(const float4*)(bp + 2 * NS);
    float4 w3 = *(const float4*)(bp + 3 * NS);
    __syncthreads();
    *(uint4*)&As[ar * 40 + ak]     = av0;
    *(uint4*)&As[ar * 40 + ak + 8] = av1;
    {
      uint2 pv;
      pv.x = (unsigned int)f2bf(w0.x) | ((unsigned int)f2bf(w1.x) << 16);
      pv.y = (unsigned int)f2bf(w2.x) | ((unsigned int)f2bf(w3.x) << 16);
      *(uint2*)&Bs[(bc + 0) * 40 + bk] = pv;
      pv.x = (unsigned int)f2bf(w0.y) | ((unsigned int)f2bf(w1.y) << 16);
      pv.y = (unsigned int)f2bf(w2.y) | ((unsigned int)f2bf(w3.y) << 16);
      *(uint2*)&Bs[(bc + 1) * 40 + bk] = pv;
      pv.x = (unsigned int)f2bf(w0.z) | ((unsigned int)f2bf(w1.z) << 16);
      pv.y = (unsigned int)f2bf(w2.z) | ((unsigned int)f2bf(w3.z) << 16);
      *(uint2*)&Bs[(bc + 2) * 40 + bk] = pv;
      pv.x = (unsigned int)f2bf(w0.w) | ((unsigned int)f2bf(w1.w) << 16);
      pv.y = (unsigned int)f2bf(w2.w) | ((unsigned int)f2bf(w3.w) << 16);
      *(uint2*)&Bs[(bc + 3) * 40 + bk] = pv;
    }
    __syncthreads();
    bf16x8 af[4], bfr[4];
#pragma unroll
    for (int m = 0; m < 4; ++m)
      af[m] = *(const bf16x8*)&As[(wr + m * 16 + fr) * 40 + fq * 8];
#pragma unroll
    for (int n = 0; n < 4; ++n)
      bfr[n] = *(const bf16x8*)&Bs[(wc + n * 16 + fr) * 40 + fq * 8];
#pragma unroll
    for (int m = 0; m < 4; ++m)
#pragma unroll
      for (int n = 0; n < 4; ++n)
        acc[m][n] = __builtin_amdgcn_mfma_f32_16x16x32_bf16(af[m], bfr[n], acc[m][n], 0, 0, 0);
  }
  if (PASS == 1) {
#pragma unroll
    for (int n = 0; n < 4; ++n) {
      int col = ct * 128 + wc + n * 16 + fr;
      float b1v = bias[(size_t)e * NS + col];
#pragma unroll
      for (int m = 0; m < 4; ++m) {
#pragma unroll
        for (int r = 0; r < 4; ++r) {
          int lrow = wr + m * 16 + fq * 4 + r;
          if (lrow < rowsvalid) {
            float v = acc[m][n][r] + b1v;
            v = 0.5f * v * (1.f + erff(v * 0.70710678118654752440f));
            Hmat[(size_t)(gbase + rt * 128 + lrow) * HID + col] = f2bf(v);
          }
        }
      }
    }
  } else {
    float b2v[4];
#pragma unroll
    for (int n = 0; n < 4; ++n)
      b2v[n] = bias[(size_t)e * NS + ct * 128 + wc + n * 16 + fr];
#pragma unroll
    for (int m = 0; m < 4; ++m) {
#pragma unroll
      for (int r = 0; r < 4; ++r) {
        int lrow = wr + m * 16 + fq * 4 + r;
        if (lrow < rowsvalid) {
          int g = gbase + rt * 128 + lrow;
          int ent = pairmap[g];
          int tok = ent >> 1;
          float s = score[ent];
#pragma unroll
          for (int n = 0; n < 4; ++n) {
            int col = ct * 128 + wc + n * 16 + fr;
            atomicAdd(&out[(size_t)tok * DIM + col], s * (acc[m][n][r] + b2v[n]));
          }
        }
      }
    }
  }
}

extern "C" void kernel_launch(void* const* d_in, const int* in_sizes, int n_in,
                              void* d_out, int out_size, void* d_ws, size_t ws_size,
                              hipStream_t stream) {
  const float* x  = (const float*)d_in[0];
  const float* W1 = (const float*)d_in[1];
  const float* b1 = (const float*)d_in[2];
  const float* W2 = (const float*)d_in[3];
  const float* b2 = (const float*)d_in[4];
  const float* Wg = (const float*)d_in[5];
  const float* bg = (const float*)d_in[6];
  float* out = (float*)d_out;
  const int N  = in_sizes[0] / DIM;   // tokens (4096)
  const int NP = N * TOPK;            // pairs (8192)
  const int NPAD = NP + 256;          // padded row space (staging over-read)
  const int MAXT = NP / 256 + NEXP;   // worst-case 256-row tiles (40)

  char* ws = (char*)d_ws;
  size_t off = 0;
  auto alloc = [&](size_t bytes) -> void* {
    void* p = ws + off;
    off = (off + bytes + 255) & ~(size_t)255;
    return p;
  };
  int*   count      = (int*)alloc(NEXP * sizeof(int));
  int*   offsets    = (int*)alloc((NEXP + 1) * sizeof(int));
  int*   tiles      = (int*)alloc((size_t)MAXT * sizeof(int));
  int*   ntiles     = (int*)alloc(sizeof(int));
  float* topk_score = (float*)alloc((size_t)NP * sizeof(float));
  int*   lists      = (int*)alloc((size_t)NEXP * N * sizeof(int));
  int*   pairmap    = (int*)alloc((size_t)NP * sizeof(int));
  // K-tiled: Xg [16][NPAD][64], Hmat [64][NPAD][64]
  unsigned short* Xg   = (unsigned short*)alloc((size_t)NPAD * DIM * sizeof(unsigned short));
  unsigned short* Hmat = (unsigned short*)alloc((size_t)NPAD * HID * sizeof(unsigned short));
  unsigned short* W1T = (unsigned short*)alloc((size_t)NEXP * DIM * HID * sizeof(unsigned short));
  unsigned short* W2T = (unsigned short*)alloc((size_t)NEXP * HID * DIM * sizeof(unsigned short));
  size_t need_full = off;

  hipMemsetAsync(count, 0, NEXP * sizeof(int), stream);
  gate_kernel<<<N, 64, 0, stream>>>(x, Wg, bg, topk_score, count, lists, N);
  offsets_kernel<<<1, 64, 0, stream>>>(count, offsets, tiles, ntiles);
  hipMemsetAsync(out, 0, (size_t)out_size * sizeof(float), stream);

  if (ws_size >= need_full) {
    gather_kernel<1><<<NP, DIM / 4, 0, stream>>>(x, offsets, lists, Xg, pairmap, N, NPAD);
    // one-time weight transpose-convert to bf16 K-tiled, single merged launch
    transpose_convert_all<<<4096, 256, 0, stream>>>(W1, W2, W1T, W2T);

    dim3 g1((HID / 128) * MAXT, 1, 1);   // 1D, tile-fastest + XCD chunk swizzle
    moe_gemm16<1><<<g1, 512, 0, stream>>>(Xg, W1T, b1, offsets, tiles, ntiles,
                                          pairmap, topk_score, Hmat, out, MAXT, NPAD);
    dim3 g2((DIM / 128) * MAXT, 1, 2);   // kz=2
    moe_gemm16<2><<<g2, 512, 0, stream>>>(Hmat, W2T, b2, offsets, tiles, ntiles,
                                          pairmap, topk_score, Hmat, out, MAXT, NPAD);
  } else {
    gather_kernel<0><<<NP, DIM / 4, 0, stream>>>(x, offsets, lists, Xg, pairmap, N, NPAD);
    const int RT = (N + 127) / 128;
    dim3 g1(RT, HID / 128, NEXP);
    moe_gemm<1><<<g1, 256, 0, stream>>>(Xg, W1, b1, offsets, pairmap, topk_score, Hmat, out);
    dim3 g2(RT, DIM / 128, NEXP);
    moe_gemm<2><<<g2, 256, 0, stream>>>(Hmat, W2, b2, offsets, pairmap, topk_score, Hmat, out);
  }
}

// Round 19
// 517.779 us; speedup vs baseline: 1.0388x; 1.0388x over previous
//
#include <hip/hip_runtime.h>
#include <math.h>

#define DIM  1024   // hidden dim D
#define NEXP 8      // experts
#define HID  4096   // expert hidden H
#define TOPK 2

typedef __attribute__((ext_vector_type(8))) short bf16x8;
typedef __attribute__((ext_vector_type(4))) float f32x4;

__device__ inline unsigned short f2bf(float f) {
  union { float f; unsigned int u; } v; v.f = f;
  unsigned int u = v.u;
  return (unsigned short)((u + 0x7FFFu + ((u >> 16) & 1u)) >> 16);
}

__device__ inline unsigned int pack2bf(float lo, float hi) {
  return (unsigned int)f2bf(lo) | ((unsigned int)f2bf(hi) << 16);
}

__device__ inline void load_lds16(const void* g, void* l) {
  __builtin_amdgcn_global_load_lds(
      (const __attribute__((address_space(1))) void*)g,
      (__attribute__((address_space(3))) void*)l, 16, 0, 0);
}

// exact-enough gelu: Abramowitz-Stegun 7.1.26 erf, |err| <= 1.5e-7 (<< bf16 rounding)
__device__ inline float gelu_f(float v) {
  float x = v * 0.70710678118654752f;
  float ax = fabsf(x);
  float t = 1.f / (1.f + 0.3275911f * ax);
  float poly = t * (0.254829592f + t * (-0.284496736f + t * (1.421413741f +
               t * (-1.453152027f + t * 1.061405429f))));
  float er = 1.f - poly * __expf(-ax * ax);
  er = (x < 0.f) ? -er : er;
  return 0.5f * v * (1.f + er);
}

// ---------------- gate: logits -> softmax -> top2 -> routing lists ----------------
__global__ void gate_kernel(const float* __restrict__ x,
                            const float* __restrict__ Wg,
                            const float* __restrict__ bg,
                            float* __restrict__ topk_score,
                            int* __restrict__ count,
                            int* __restrict__ lists,
                            int N) {
  int n = blockIdx.x;
  if (n >= N) return;
  int lane = threadIdx.x;
  float acc[NEXP];
#pragma unroll
  for (int e = 0; e < NEXP; ++e) acc[e] = 0.f;
  const float* xr = x + (size_t)n * DIM;
  for (int d = lane; d < DIM; d += 64) {
    float xv = xr[d];
    const float* w = Wg + (size_t)d * NEXP;
#pragma unroll
    for (int e = 0; e < NEXP; ++e) acc[e] += xv * w[e];
  }
#pragma unroll
  for (int off = 32; off > 0; off >>= 1) {
#pragma unroll
    for (int e = 0; e < NEXP; ++e) acc[e] += __shfl_xor(acc[e], off, 64);
  }
  if (lane == 0) {
    float l[NEXP];
#pragma unroll
    for (int e = 0; e < NEXP; ++e) l[e] = acc[e] + bg[e];
    float m = l[0];
#pragma unroll
    for (int e = 1; e < NEXP; ++e) m = fmaxf(m, l[e]);
    float p[NEXP];
    float s = 0.f;
#pragma unroll
    for (int e = 0; e < NEXP; ++e) { p[e] = expf(l[e] - m); s += p[e]; }
    int i0 = 0;
#pragma unroll
    for (int e = 1; e < NEXP; ++e) if (l[e] > l[i0]) i0 = e;
    int i1 = (i0 == 0) ? 1 : 0;
#pragma unroll
    for (int e = 0; e < NEXP; ++e) if (e != i0 && l[e] > l[i1]) i1 = e;
    float inv = 1.f / s;
    topk_score[n * TOPK + 0] = p[i0] * inv;
    topk_score[n * TOPK + 1] = p[i1] * inv;
    int pos0 = atomicAdd(&count[i0], 1);
    lists[(size_t)i0 * N + pos0] = n * TOPK + 0;
    int pos1 = atomicAdd(&count[i1], 1);
    lists[(size_t)i1 * N + pos1] = n * TOPK + 1;
  }
}

// offsets + flattened 128-row tile table (kills dead blocks)
__global__ void offsets_kernel(const int* __restrict__ count, int* __restrict__ offsets,
                               int* __restrict__ tiles, int* __restrict__ ntiles) {
  if (threadIdx.x == 0 && blockIdx.x == 0) {
    int s = 0, nt = 0;
    for (int e = 0; e < NEXP; ++e) {
      offsets[e] = s;
      int c = count[e];
      s += c;
      int rts = (c + 127) >> 7;
      for (int i = 0; i < rts; ++i) tiles[nt++] = (e << 16) | i;
    }
    offsets[NEXP] = s;
    ntiles[0] = nt;
  }
}

// gather token rows (sorted by expert) into bf16 Xg; record pair mapping
// TILED=1: Xg layout [kb=DIM/64][NPAD][64] (K-tiled, contiguous staging blocks)
template <int TILED>
__global__ void gather_kernel(const float* __restrict__ x,
                              const int* __restrict__ offsets,
                              const int* __restrict__ lists,
                              unsigned short* __restrict__ Xg,
                              int* __restrict__ pairmap,
                              int N, int NPAD) {
  int g = blockIdx.x;
  int e = 0;
  while (e < NEXP - 1 && g >= offsets[e + 1]) ++e;
  int i = g - offsets[e];
  int ent = lists[(size_t)e * N + i];
  int tok = ent >> 1;
  if (threadIdx.x == 0) pairmap[g] = ent;
  int d0 = threadIdx.x * 4;
  float4 v = *((const float4*)(x + (size_t)tok * DIM + d0));
  ushort4 o;
  o.x = f2bf(v.x); o.y = f2bf(v.y); o.z = f2bf(v.z); o.w = f2bf(v.w);
  if (TILED) {
    *(ushort4*)(Xg + ((size_t)(d0 >> 6) * NPAD + g) * 64 + (d0 & 63)) = o;
  } else {
    *(ushort4*)(Xg + (size_t)g * DIM + d0) = o;
  }
}

// --- merged transpose-convert v2: W1 [e][1024][4096] and W2 [e][4096][1024] fp32
//     -> W1T/W2T [e][R/64][C][64] bf16 (K-tiled). One launch; per 64x64 tile:
//     pack row-pairs to u32 in regs -> ds_write_b32 into padded [64][33] u32 tile
//     (2-way max, free) -> uint4 reads (8 bf16/b128) -> coalesced 16B stores.
//     LDS ops/tile/thread: 8 b32-writes + 2 b128-reads (was 16 b16-w + 4 b64-r).
__global__ __launch_bounds__(256) void transpose_convert_all(
    const float* __restrict__ W1, const float* __restrict__ W2,
    unsigned short* __restrict__ W1T, unsigned short* __restrict__ W2T) {
  int idx = blockIdx.x;
  const float* src; unsigned short* dst; int C, r0, c0base;
  if (idx < 2048) {            // W1: 8 experts x (1024/64 rt) x (4096/256 ct4)
    const int e = idx >> 8, rem = idx & 255;
    C = 4096;
    r0 = (rem >> 4) * 64;
    c0base = (rem & 15) * 256;
    src = W1 + (size_t)e * 1024 * 4096;
    dst = W1T + (size_t)e * 1024 * 4096;
  } else {                     // W2: 8 experts x (4096/64 rt) x (1024/256 ct4)
    idx -= 2048;
    const int e = idx >> 8, rem = idx & 255;
    C = 1024;
    r0 = (rem >> 2) * 64;
    c0base = (rem & 3) * 256;
    src = W2 + (size_t)e * 4096 * 1024;
    dst = W2T + (size_t)e * 4096 * 1024;
  }
  __shared__ unsigned int Ts32[64][33];   // [col][row-pair], +1 pad
  const int t = threadIdx.x;
  const int rr2 = t >> 4;            // row-pair base 0..15
  const int cc  = (t & 15) * 4;      // 4 columns
  const int rc  = t >> 2;            // read: column 0..63
  const int part = t & 3;            // read: quarter 0..3
  const size_t kbbase = (size_t)(r0 >> 6) * C;
  for (int sub = 0; sub < 4; ++sub) {
    const int c0 = c0base + sub * 64;
#pragma unroll
    for (int p = 0; p < 2; ++p) {
      const int r2 = rr2 + p * 16;         // row-pair index 0..31
      const int r = r2 * 2;
      float4 va = *(const float4*)(src + (size_t)(r0 + r) * C + c0 + cc);
      float4 vb = *(const float4*)(src + (size_t)(r0 + r + 1) * C + c0 + cc);
      Ts32[cc + 0][r2] = pack2bf(va.x, vb.x);
      Ts32[cc + 1][r2] = pack2bf(va.y, vb.y);
      Ts32[cc + 2][r2] = pack2bf(va.z, vb.z);
      Ts32[cc + 3][r2] = pack2bf(va.w, vb.w);
    }
    __syncthreads();
    {
      uint4 x0 = *(const uint4*)&Ts32[rc][part * 8];
      uint4 x1 = *(const uint4*)&Ts32[rc][part * 8 + 4];
      unsigned short* dp = dst + (kbbase + (c0 + rc)) * 64 + part * 16;
      *(uint4*)(dp) = x0;        // rows part*16 .. +7 of column rc
      *(uint4*)(dp + 8) = x1;    // rows part*16+8 .. +15
    }
    __syncthreads();
  }
}

// ---- grouped bf16 GEMM (r15/r17 exact, best of 13 variants: 169.5-173 us/pass):
// 128x128 tile, 4 waves, BK=32, SINGLE-buffered 16 KB LDS -> high blocks/CU;
// cross-block TLP at 256-thr block size sustains the ~7 TB/s staging rate
// (512-thr blocks measured at only ~4.6-5.1 TB/s -- r14/r18). Linear LDS,
// linear lane-contiguous global_load_lds from K-tiled operands.
// 1D grid, tile-fastest, bijective chunked XCD swizzle.
// PASS 1: Hmat_t = gelu(Xg_t * W1T^T + b1)   (K-tiled output for pass-2 staging)
// PASS 2 (kz=0,1): out[tok] += score * (Hmat_kslice * W2T_kslice^T [+ b2 if kz==0])
template <int PASS>
__global__ __launch_bounds__(256) void moe_gemm14(
    const unsigned short* __restrict__ Asrc,
    const unsigned short* __restrict__ Bt,
    const float* __restrict__ bias,
    const int* __restrict__ offsets,
    const int* __restrict__ tiles,
    const int* __restrict__ ntiles,
    const int* __restrict__ pairmap,
    const float* __restrict__ score,
    unsigned short* __restrict__ Hmat,
    float* __restrict__ out,
    int maxt, int NPAD) {
  constexpr int K  = (PASS == 1) ? DIM : HID;   // reduction dim
  constexpr int NS = (PASS == 1) ? HID : DIM;   // output width
  constexpr int KS = (PASS == 1) ? 1 : 2;       // k-split (pass2: 2x blocks)
  constexpr int KL = K / KS;
  constexpr int NT = KL / 32;                   // K-steps (32 or 64)
  constexpr int KBK = K / 64;                   // 64-elem k-blocks in operands

  // bijective chunked XCD swizzle (m204)
  const unsigned orig = blockIdx.x;
  const unsigned nwg = gridDim.x;
  const unsigned q = nwg >> 3, r8 = nwg & 7;
  const unsigned xcd = orig & 7, p8 = orig >> 3;
  const unsigned id = (xcd < r8 ? xcd * (q + 1) : r8 * (q + 1) + (xcd - r8) * q) + p8;
  const int tt = (int)(id % (unsigned)maxt);    // row-tile (fastest)
  const int ct = (int)(id / (unsigned)maxt);    // column tile (128 wide)

  if (tt >= ntiles[0]) return;
  const int pk = tiles[tt];
  const int e  = pk >> 16;
  const int rt = pk & 0xffff;
  const int gbase = offsets[e];
  const int nc = offsets[e + 1] - gbase;
  const int rowsvalid = min(128, nc - rt * 128);
  const int kz = (PASS == 1) ? 0 : blockIdx.z;
  const int kb0 = (kz * KL) >> 6;               // first 64-elem k-block of this slice

  __shared__ unsigned short As[128 * 32];   // 8 KB
  __shared__ unsigned short Bs[128 * 32];   // 8 KB  -> 16 KB total

  const int tid  = threadIdx.x;
  const int lane = tid & 63;
  const int wid  = tid >> 6;        // 0..3
  const int wr = (wid >> 1) * 64;   // wave row base: 0,64
  const int wc = (wid & 1) * 64;    // wave col base: 0,64
  const int fr = lane & 15;
  const int fq = lane >> 4;

  f32x4 acc[4][4];
#pragma unroll
  for (int m = 0; m < 4; ++m)
#pragma unroll
    for (int n = 0; n < 4; ++n) acc[m][n] = (f32x4){0.f, 0.f, 0.f, 0.f};

  // K-tiled bases; step t reads half-slab: kb = kb0 + (t>>1), k-half = t&1
  const unsigned short* Ab = Asrc + ((size_t)kb0 * NPAD + (gbase + rt * 128)) * 64;
  const unsigned short* Bb = Bt + (((size_t)e * KBK + kb0) * NS + (size_t)ct * 128) * 64;

  for (int t = 0; t < NT; ++t) {
    // stage tile t: 4 load_lds per thread; per row-half 64 B contiguous
    {
      const unsigned short* ga = Ab + (size_t)(t >> 1) * ((size_t)NPAD * 64) + (t & 1) * 32;
      const unsigned short* gb = Bb + (size_t)(t >> 1) * ((size_t)NS * 64) + (t & 1) * 32;
#pragma unroll
      for (int i = 0; i < 2; ++i) {
        const int c = i * 256 + tid;            // 16B-unit index, 0..511
        const int row = c >> 2;
        const int u = c & 3;
        load_lds16(ga + (size_t)row * 64 + u * 8, (char*)As + c * 16);
        load_lds16(gb + (size_t)row * 64 + u * 8, (char*)Bs + c * 16);
      }
    }
    __syncthreads();   // compiler drains vmcnt(0): tile t resident in LDS

    {
      bf16x8 af[4], bf[4];
#pragma unroll
      for (int m = 0; m < 4; ++m)
        af[m] = *(const bf16x8*)&As[(wr + m * 16 + fr) * 32 + fq * 8];
#pragma unroll
      for (int n = 0; n < 4; ++n)
        bf[n] = *(const bf16x8*)&Bs[(wc + n * 16 + fr) * 32 + fq * 8];
#pragma unroll
      for (int m = 0; m < 4; ++m)
#pragma unroll
        for (int n = 0; n < 4; ++n)
          acc[m][n] = __builtin_amdgcn_mfma_f32_16x16x32_bf16(af[m], bf[n], acc[m][n], 0, 0, 0);
    }
    __syncthreads();   // all waves done reading -> safe to overwrite next iter
  }

  if (PASS == 1) {
    const size_t cb = (size_t)(ct * 2 + (wc >> 6));   // output k-block in Hmat_t
#pragma unroll
    for (int n = 0; n < 4; ++n) {
      const int col = ct * 128 + wc + n * 16 + fr;
      const int cl = n * 16 + fr;                     // col within 64-block
      const float b1v = bias[(size_t)e * NS + col];
#pragma unroll
      for (int m = 0; m < 4; ++m) {
#pragma unroll
        for (int r = 0; r < 4; ++r) {
          const int lrow = wr + m * 16 + fq * 4 + r;
          if (lrow < rowsvalid) {
            float v = gelu_f(acc[m][n][r] + b1v);
            Hmat[(cb * NPAD + (gbase + rt * 128 + lrow)) * 64 + cl] = f2bf(v);
          }
        }
      }
    }
  } else {
    float b2v[4];
#pragma unroll
    for (int n = 0; n < 4; ++n)
      b2v[n] = (kz == 0) ? bias[(size_t)e * NS + ct * 128 + wc + n * 16 + fr] : 0.f;
#pragma unroll
    for (int m = 0; m < 4; ++m) {
#pragma unroll
      for (int r = 0; r < 4; ++r) {
        const int lrow = wr + m * 16 + fq * 4 + r;
        if (lrow < rowsvalid) {
          const int g = gbase + rt * 128 + lrow;
          const int ent = pairmap[g];
          const int tok = ent >> 1;
          const float s = score[ent];
#pragma unroll
          for (int n = 0; n < 4; ++n) {
            const int col = ct * 128 + wc + n * 16 + fr;
            atomicAdd(&out[(size_t)tok * DIM + col], s * (acc[m][n][r] + b2v[n]));
          }
        }
      }
    }
  }
}

// ============== fallback: round-1 GEMM (fp32 weights converted in-loop) ==============
template <int PASS>
__global__ __launch_bounds__(256) void moe_gemm(
    const unsigned short* __restrict__ Asrc,
    const float* __restrict__ Bsrc,
    const float* __restrict__ bias,
    const int* __restrict__ offsets,
    const int* __restrict__ pairmap,
    const float* __restrict__ score,
    unsigned short* __restrict__ Hmat,
    float* __restrict__ out) {
  constexpr int K  = (PASS == 1) ? DIM : HID;
  constexpr int NS = (PASS == 1) ? HID : DIM;
  const int e = blockIdx.z;
  const int gbase = offsets[e];
  const int nc = offsets[e + 1] - gbase;
  const int rt = blockIdx.x;
  if (rt * 128 >= nc) return;
  const int rowsvalid = min(128, nc - rt * 128);
  const int ct = blockIdx.y;
  __shared__ unsigned short As[128 * 40];
  __shared__ unsigned short Bs[128 * 40];
  const int tid  = threadIdx.x;
  const int lane = tid & 63;
  const int wid  = tid >> 6;
  const int wr = (wid >> 1) * 64;
  const int wc = (wid & 1) * 64;
  const int fr = lane & 15;
  const int fq = lane >> 4;
  f32x4 acc[4][4];
#pragma unroll
  for (int m = 0; m < 4; ++m)
#pragma unroll
    for (int n = 0; n < 4; ++n) acc[m][n] = (f32x4){0.f, 0.f, 0.f, 0.f};
  const int ar = tid >> 1;
  const int ak = (tid & 1) * 16;
  int arow = rt * 128 + ((ar < rowsvalid) ? ar : 0);
  const unsigned short* Aptr = Asrc + (size_t)(gbase + arow) * K + ak;
  const int bc = (tid & 31) * 4;
  const int bk = (tid >> 5) * 4;
  const float* Bptr = Bsrc + (size_t)e * K * NS + (size_t)bk * NS + ct * 128 + bc;
  for (int k0 = 0; k0 < K; k0 += 32) {
    uint4 av0 = *(const uint4*)(Aptr + k0);
    uint4 av1 = *(const uint4*)(Aptr + k0 + 8);
    const float* bp = Bptr + (size_t)k0 * NS;
    float4 w0 = *(const float4*)(bp);
    float4 w1 = *(const float4*)(bp + NS);
    float4 w2 = *(const float4*)(bp + 2 * NS);
    float4 w3 = *(const float4*)(bp + 3 * NS);
    __syncthreads();
    *(uint4*)&As[ar * 40 + ak]     = av0;
    *(uint4*)&As[ar * 40 + ak + 8] = av1;
    {
      uint2 pv;
      pv.x = (unsigned int)f2bf(w0.x) | ((unsigned int)f2bf(w1.x) << 16);
      pv.y = (unsigned int)f2bf(w2.x) | ((unsigned int)f2bf(w3.x) << 16);
      *(uint2*)&Bs[(bc + 0) * 40 + bk] = pv;
      pv.x = (unsigned int)f2bf(w0.y) | ((unsigned int)f2bf(w1.y) << 16);
      pv.y = (unsigned int)f2bf(w2.y) | ((unsigned int)f2bf(w3.y) << 16);
      *(uint2*)&Bs[(bc + 1) * 40 + bk] = pv;
      pv.x = (unsigned int)f2bf(w0.z) | ((unsigned int)f2bf(w1.z) << 16);
      pv.y = (unsigned int)f2bf(w2.z) | ((unsigned int)f2bf(w3.z) << 16);
      *(uint2*)&Bs[(bc + 2) * 40 + bk] = pv;
      pv.x = (unsigned int)f2bf(w0.w) | ((unsigned int)f2bf(w1.w) << 16);
      pv.y = (unsigned int)f2bf(w2.w) | ((unsigned int)f2bf(w3.w) << 16);
      *(uint2*)&Bs[(bc + 3) * 40 + bk] = pv;
    }
    __syncthreads();
    bf16x8 af[4], bfr[4];
#pragma unroll
    for (int m = 0; m < 4; ++m)
      af[m] = *(const bf16x8*)&As[(wr + m * 16 + fr) * 40 + fq * 8];
#pragma unroll
    for (int n = 0; n < 4; ++n)
      bfr[n] = *(const bf16x8*)&Bs[(wc + n * 16 + fr) * 40 + fq * 8];
#pragma unroll
    for (int m = 0; m < 4; ++m)
#pragma unroll
      for (int n = 0; n < 4; ++n)
        acc[m][n] = __builtin_amdgcn_mfma_f32_16x16x32_bf16(af[m], bfr[n], acc[m][n], 0, 0, 0);
  }
  if (PASS == 1) {
#pragma unroll
    for (int n = 0; n < 4; ++n) {
      int col = ct * 128 + wc + n * 16 + fr;
      float b1v = bias[(size_t)e * NS + col];
#pragma unroll
      for (int m = 0; m < 4; ++m) {
#pragma unroll
        for (int r = 0; r < 4; ++r) {
          int lrow = wr + m * 16 + fq * 4 + r;
          if (lrow < rowsvalid) {
            float v = acc[m][n][r] + b1v;
            v = 0.5f * v * (1.f + erff(v * 0.70710678118654752440f));
            Hmat[(size_t)(gbase + rt * 128 + lrow) * HID + col] = f2bf(v);
          }
        }
      }
    }
  } else {
    float b2v[4];
#pragma unroll
    for (int n = 0; n < 4; ++n)
      b2v[n] = bias[(size_t)e * NS + ct * 128 + wc + n * 16 + fr];
#pragma unroll
    for (int m = 0; m < 4; ++m) {
#pragma unroll
      for (int r = 0; r < 4; ++r) {
        int lrow = wr + m * 16 + fq * 4 + r;
        if (lrow < rowsvalid) {
          int g = gbase + rt * 128 + lrow;
          int ent = pairmap[g];
          int tok = ent >> 1;
          float s = score[ent];
#pragma unroll
          for (int n = 0; n < 4; ++n) {
            int col = ct * 128 + wc + n * 16 + fr;
            atomicAdd(&out[(size_t)tok * DIM + col], s * (acc[m][n][r] + b2v[n]));
          }
        }
      }
    }
  }
}

extern "C" void kernel_launch(void* const* d_in, const int* in_sizes, int n_in,
                              void* d_out, int out_size, void* d_ws, size_t ws_size,
                              hipStream_t stream) {
  const float* x  = (const float*)d_in[0];
  const float* W1 = (const float*)d_in[1];
  const float* b1 = (const float*)d_in[2];
  const float* W2 = (const float*)d_in[3];
  const float* b2 = (const float*)d_in[4];
  const float* Wg = (const float*)d_in[5];
  const float* bg = (const float*)d_in[6];
  float* out = (float*)d_out;
  const int N  = in_sizes[0] / DIM;   // tokens (4096)
  const int NP = N * TOPK;            // pairs (8192)
  const int NPAD = NP + 256;          // padded row space (staging over-read)
  const int MAXT = NP / 128 + NEXP;   // worst-case 128-row tiles (72)

  char* ws = (char*)d_ws;
  size_t off = 0;
  auto alloc = [&](size_t bytes) -> void* {
    void* p = ws + off;
    off = (off + bytes + 255) & ~(size_t)255;
    return p;
  };
  int*   count      = (int*)alloc(NEXP * sizeof(int));
  int*   offsets    = (int*)alloc((NEXP + 1) * sizeof(int));
  int*   tiles      = (int*)alloc((size_t)MAXT * sizeof(int));
  int*   ntiles     = (int*)alloc(sizeof(int));
  float* topk_score = (float*)alloc((size_t)NP * sizeof(float));
  int*   lists      = (int*)alloc((size_t)NEXP * N * sizeof(int));
  int*   pairmap    = (int*)alloc((size_t)NP * sizeof(int));
  // K-tiled: Xg [16][NPAD][64], Hmat [64][NPAD][64]
  unsigned short* Xg   = (unsigned short*)alloc((size_t)NPAD * DIM * sizeof(unsigned short));
  unsigned short* Hmat = (unsigned short*)alloc((size_t)NPAD * HID * sizeof(unsigned short));
  unsigned short* W1T = (unsigned short*)alloc((size_t)NEXP * DIM * HID * sizeof(unsigned short));
  unsigned short* W2T = (unsigned short*)alloc((size_t)NEXP * HID * DIM * sizeof(unsigned short));
  size_t need_full = off;

  hipMemsetAsync(count, 0, NEXP * sizeof(int), stream);
  gate_kernel<<<N, 64, 0, stream>>>(x, Wg, bg, topk_score, count, lists, N);
  offsets_kernel<<<1, 64, 0, stream>>>(count, offsets, tiles, ntiles);
  hipMemsetAsync(out, 0, (size_t)out_size * sizeof(float), stream);

  if (ws_size >= need_full) {
    gather_kernel<1><<<NP, DIM / 4, 0, stream>>>(x, offsets, lists, Xg, pairmap, N, NPAD);
    // one-time weight transpose-convert to bf16 K-tiled, single merged launch (v2)
    transpose_convert_all<<<4096, 256, 0, stream>>>(W1, W2, W1T, W2T);

    dim3 g1((HID / 128) * MAXT, 1, 1);   // 1D, tile-fastest + XCD chunk swizzle
    moe_gemm14<1><<<g1, 256, 0, stream>>>(Xg, W1T, b1, offsets, tiles, ntiles,
                                          pairmap, topk_score, Hmat, out, MAXT, NPAD);
    dim3 g2((DIM / 128) * MAXT, 1, 2);   // kz=2
    moe_gemm14<2><<<g2, 256, 0, stream>>>(Hmat, W2T, b2, offsets, tiles, ntiles,
                                          pairmap, topk_score, Hmat, out, MAXT, NPAD);
  } else {
    gather_kernel<0><<<NP, DIM / 4, 0, stream>>>(x, offsets, lists, Xg, pairmap, N, NPAD);
    const int RT = (N + 127) / 128;
    dim3 g1(RT, HID / 128, NEXP);
    moe_gemm<1><<<g1, 256, 0, stream>>>(Xg, W1, b1, offsets, pairmap, topk_score, Hmat, out);
    dim3 g2(RT, DIM / 128, NEXP);
    moe_gemm<2><<<g2, 256, 0, stream>>>(Hmat, W2, b2, offsets, pairmap, topk_score, Hmat, out);
  }
}

// Round 20
// 513.650 us; speedup vs baseline: 1.0471x; 1.0080x over previous
//
#include <hip/hip_runtime.h>
#include <math.h>

#define DIM  1024   // hidden dim D
#define NEXP 8      // experts
#define HID  4096   // expert hidden H
#define TOPK 2

typedef __attribute__((ext_vector_type(8))) short bf16x8;
typedef __attribute__((ext_vector_type(4))) float f32x4;

__device__ inline unsigned short f2bf(float f) {
  union { float f; unsigned int u; } v; v.f = f;
  unsigned int u = v.u;
  return (unsigned short)((u + 0x7FFFu + ((u >> 16) & 1u)) >> 16);
}

__device__ inline unsigned int pack2bf(float lo, float hi) {
  return (unsigned int)f2bf(lo) | ((unsigned int)f2bf(hi) << 16);
}

__device__ inline void load_lds16(const void* g, void* l) {
  __builtin_amdgcn_global_load_lds(
      (const __attribute__((address_space(1))) void*)g,
      (__attribute__((address_space(3))) void*)l, 16, 0, 0);
}

// exact-enough gelu: Abramowitz-Stegun 7.1.26 erf, |err| <= 1.5e-7 (<< bf16 rounding)
__device__ inline float gelu_f(float v) {
  float x = v * 0.70710678118654752f;
  float ax = fabsf(x);
  float t = 1.f / (1.f + 0.3275911f * ax);
  float poly = t * (0.254829592f + t * (-0.284496736f + t * (1.421413741f +
               t * (-1.453152027f + t * 1.061405429f))));
  float er = 1.f - poly * __expf(-ax * ax);
  er = (x < 0.f) ? -er : er;
  return 0.5f * v * (1.f + er);
}

// ---------------- gate v2: 4 waves/block, one token/wave, vectorized Wg loads ----------------
// Per d handled by a lane: Wg row [d][0..7] as two float4 (32B coalesced across lanes,
// consecutive lanes hit consecutive rows) + scalar x[d] (coalesced). 48 vec loads/lane
// vs 144 scalar in v1.
__global__ __launch_bounds__(256) void gate_kernel(
    const float* __restrict__ x,
    const float* __restrict__ Wg,
    const float* __restrict__ bg,
    float* __restrict__ topk_score,
    int* __restrict__ count,
    int* __restrict__ lists,
    int N) {
  int n = blockIdx.x * 4 + (threadIdx.x >> 6);
  if (n >= N) return;
  int lane = threadIdx.x & 63;
  float acc[NEXP];
#pragma unroll
  for (int e = 0; e < NEXP; ++e) acc[e] = 0.f;
  const float* xr = x + (size_t)n * DIM;
#pragma unroll
  for (int i = 0; i < DIM / 64; ++i) {
    int d = lane + i * 64;
    float xv = xr[d];
    const float* w = Wg + (size_t)d * NEXP;
    float4 w0 = *(const float4*)(w);
    float4 w1 = *(const float4*)(w + 4);
    acc[0] += xv * w0.x; acc[1] += xv * w0.y; acc[2] += xv * w0.z; acc[3] += xv * w0.w;
    acc[4] += xv * w1.x; acc[5] += xv * w1.y; acc[6] += xv * w1.z; acc[7] += xv * w1.w;
  }
#pragma unroll
  for (int off = 32; off > 0; off >>= 1) {
#pragma unroll
    for (int e = 0; e < NEXP; ++e) acc[e] += __shfl_xor(acc[e], off, 64);
  }
  if (lane == 0) {
    float l[NEXP];
#pragma unroll
    for (int e = 0; e < NEXP; ++e) l[e] = acc[e] + bg[e];
    float m = l[0];
#pragma unroll
    for (int e = 1; e < NEXP; ++e) m = fmaxf(m, l[e]);
    float p[NEXP];
    float s = 0.f;
#pragma unroll
    for (int e = 0; e < NEXP; ++e) { p[e] = expf(l[e] - m); s += p[e]; }
    // top-2 by logit, ties -> lowest index (matches lax.top_k)
    int i0 = 0;
#pragma unroll
    for (int e = 1; e < NEXP; ++e) if (l[e] > l[i0]) i0 = e;
    int i1 = (i0 == 0) ? 1 : 0;
#pragma unroll
    for (int e = 0; e < NEXP; ++e) if (e != i0 && l[e] > l[i1]) i1 = e;
    float inv = 1.f / s;
    topk_score[n * TOPK + 0] = p[i0] * inv;
    topk_score[n * TOPK + 1] = p[i1] * inv;
    int pos0 = atomicAdd(&count[i0], 1);
    lists[(size_t)i0 * N + pos0] = n * TOPK + 0;
    int pos1 = atomicAdd(&count[i1], 1);
    lists[(size_t)i1 * N + pos1] = n * TOPK + 1;
  }
}

// offsets + flattened 128-row tile table (kills dead blocks)
__global__ void offsets_kernel(const int* __restrict__ count, int* __restrict__ offsets,
                               int* __restrict__ tiles, int* __restrict__ ntiles) {
  if (threadIdx.x == 0 && blockIdx.x == 0) {
    int s = 0, nt = 0;
    for (int e = 0; e < NEXP; ++e) {
      offsets[e] = s;
      int c = count[e];
      s += c;
      int rts = (c + 127) >> 7;
      for (int i = 0; i < rts; ++i) tiles[nt++] = (e << 16) | i;
    }
    offsets[NEXP] = s;
    ntiles[0] = nt;
  }
}

// gather token rows (sorted by expert) into bf16 Xg; record pair mapping
// TILED=1: Xg layout [kb=DIM/64][NPAD][64] (K-tiled, contiguous staging blocks)
template <int TILED>
__global__ void gather_kernel(const float* __restrict__ x,
                              const int* __restrict__ offsets,
                              const int* __restrict__ lists,
                              unsigned short* __restrict__ Xg,
                              int* __restrict__ pairmap,
                              int N, int NPAD) {
  int g = blockIdx.x;
  int e = 0;
  while (e < NEXP - 1 && g >= offsets[e + 1]) ++e;
  int i = g - offsets[e];
  int ent = lists[(size_t)e * N + i];
  int tok = ent >> 1;
  if (threadIdx.x == 0) pairmap[g] = ent;
  int d0 = threadIdx.x * 4;
  float4 v = *((const float4*)(x + (size_t)tok * DIM + d0));
  ushort4 o;
  o.x = f2bf(v.x); o.y = f2bf(v.y); o.z = f2bf(v.z); o.w = f2bf(v.w);
  if (TILED) {
    *(ushort4*)(Xg + ((size_t)(d0 >> 6) * NPAD + g) * 64 + (d0 & 63)) = o;
  } else {
    *(ushort4*)(Xg + (size_t)g * DIM + d0) = o;
  }
}

// --- merged transpose-convert v2: W1 [e][1024][4096] and W2 [e][4096][1024] fp32
//     -> W1T/W2T [e][R/64][C][64] bf16 (K-tiled). One launch; u32 row-pair packing.
__global__ __launch_bounds__(256) void transpose_convert_all(
    const float* __restrict__ W1, const float* __restrict__ W2,
    unsigned short* __restrict__ W1T, unsigned short* __restrict__ W2T) {
  int idx = blockIdx.x;
  const float* src; unsigned short* dst; int C, r0, c0base;
  if (idx < 2048) {            // W1: 8 experts x (1024/64 rt) x (4096/256 ct4)
    const int e = idx >> 8, rem = idx & 255;
    C = 4096;
    r0 = (rem >> 4) * 64;
    c0base = (rem & 15) * 256;
    src = W1 + (size_t)e * 1024 * 4096;
    dst = W1T + (size_t)e * 1024 * 4096;
  } else {                     // W2: 8 experts x (4096/64 rt) x (1024/256 ct4)
    idx -= 2048;
    const int e = idx >> 8, rem = idx & 255;
    C = 1024;
    r0 = (rem >> 2) * 64;
    c0base = (rem & 3) * 256;
    src = W2 + (size_t)e * 4096 * 1024;
    dst = W2T + (size_t)e * 4096 * 1024;
  }
  __shared__ unsigned int Ts32[64][33];   // [col][row-pair], +1 pad
  const int t = threadIdx.x;
  const int rr2 = t >> 4;            // row-pair base 0..15
  const int cc  = (t & 15) * 4;      // 4 columns
  const int rc  = t >> 2;            // read: column 0..63
  const int part = t & 3;            // read: quarter 0..3
  const size_t kbbase = (size_t)(r0 >> 6) * C;
  for (int sub = 0; sub < 4; ++sub) {
    const int c0 = c0base + sub * 64;
#pragma unroll
    for (int p = 0; p < 2; ++p) {
      const int r2 = rr2 + p * 16;         // row-pair index 0..31
      const int r = r2 * 2;
      float4 va = *(const float4*)(src + (size_t)(r0 + r) * C + c0 + cc);
      float4 vb = *(const float4*)(src + (size_t)(r0 + r + 1) * C + c0 + cc);
      Ts32[cc + 0][r2] = pack2bf(va.x, vb.x);
      Ts32[cc + 1][r2] = pack2bf(va.y, vb.y);
      Ts32[cc + 2][r2] = pack2bf(va.z, vb.z);
      Ts32[cc + 3][r2] = pack2bf(va.w, vb.w);
    }
    __syncthreads();
    {
      uint4 x0 = *(const uint4*)&Ts32[rc][part * 8];
      uint4 x1 = *(const uint4*)&Ts32[rc][part * 8 + 4];
      unsigned short* dp = dst + (kbbase + (c0 + rc)) * 64 + part * 16;
      *(uint4*)(dp) = x0;
      *(uint4*)(dp + 8) = x1;
    }
    __syncthreads();
  }
}

// ---- grouped bf16 GEMM (r15/r17 exact, best of 13 variants: 169.5-173 us/pass):
// 128x128 tile, 4 waves, BK=32, SINGLE-buffered 16 KB LDS. At the measured
// staging-path ceiling: 1.18 GB staged/pass / ~7.0 TB/s = 169 us (fits within 2%).
// Linear LDS, linear lane-contiguous global_load_lds from K-tiled operands.
// 1D grid, tile-fastest, bijective chunked XCD swizzle.
// PASS 1: Hmat_t = gelu(Xg_t * W1T^T + b1)   (K-tiled output for pass-2 staging)
// PASS 2 (kz=0,1): out[tok] += score * (Hmat_kslice * W2T_kslice^T [+ b2 if kz==0])
template <int PASS>
__global__ __launch_bounds__(256) void moe_gemm14(
    const unsigned short* __restrict__ Asrc,
    const unsigned short* __restrict__ Bt,
    const float* __restrict__ bias,
    const int* __restrict__ offsets,
    const int* __restrict__ tiles,
    const int* __restrict__ ntiles,
    const int* __restrict__ pairmap,
    const float* __restrict__ score,
    unsigned short* __restrict__ Hmat,
    float* __restrict__ out,
    int maxt, int NPAD) {
  constexpr int K  = (PASS == 1) ? DIM : HID;   // reduction dim
  constexpr int NS = (PASS == 1) ? HID : DIM;   // output width
  constexpr int KS = (PASS == 1) ? 1 : 2;       // k-split (pass2: 2x blocks)
  constexpr int KL = K / KS;
  constexpr int NT = KL / 32;                   // K-steps (32 or 64)
  constexpr int KBK = K / 64;                   // 64-elem k-blocks in operands

  // bijective chunked XCD swizzle (m204)
  const unsigned orig = blockIdx.x;
  const unsigned nwg = gridDim.x;
  const unsigned q = nwg >> 3, r8 = nwg & 7;
  const unsigned xcd = orig & 7, p8 = orig >> 3;
  const unsigned id = (xcd < r8 ? xcd * (q + 1) : r8 * (q + 1) + (xcd - r8) * q) + p8;
  const int tt = (int)(id % (unsigned)maxt);    // row-tile (fastest)
  const int ct = (int)(id / (unsigned)maxt);    // column tile (128 wide)

  if (tt >= ntiles[0]) return;
  const int pk = tiles[tt];
  const int e  = pk >> 16;
  const int rt = pk & 0xffff;
  const int gbase = offsets[e];
  const int nc = offsets[e + 1] - gbase;
  const int rowsvalid = min(128, nc - rt * 128);
  const int kz = (PASS == 1) ? 0 : blockIdx.z;
  const int kb0 = (kz * KL) >> 6;               // first 64-elem k-block of this slice

  __shared__ unsigned short As[128 * 32];   // 8 KB
  __shared__ unsigned short Bs[128 * 32];   // 8 KB  -> 16 KB total

  const int tid  = threadIdx.x;
  const int lane = tid & 63;
  const int wid  = tid >> 6;        // 0..3
  const int wr = (wid >> 1) * 64;   // wave row base: 0,64
  const int wc = (wid & 1) * 64;    // wave col base: 0,64
  const int fr = lane & 15;
  const int fq = lane >> 4;

  f32x4 acc[4][4];
#pragma unroll
  for (int m = 0; m < 4; ++m)
#pragma unroll
    for (int n = 0; n < 4; ++n) acc[m][n] = (f32x4){0.f, 0.f, 0.f, 0.f};

  // K-tiled bases; step t reads half-slab: kb = kb0 + (t>>1), k-half = t&1
  const unsigned short* Ab = Asrc + ((size_t)kb0 * NPAD + (gbase + rt * 128)) * 64;
  const unsigned short* Bb = Bt + (((size_t)e * KBK + kb0) * NS + (size_t)ct * 128) * 64;

  for (int t = 0; t < NT; ++t) {
    // stage tile t: 4 load_lds per thread; per row-half 64 B contiguous
    {
      const unsigned short* ga = Ab + (size_t)(t >> 1) * ((size_t)NPAD * 64) + (t & 1) * 32;
      const unsigned short* gb = Bb + (size_t)(t >> 1) * ((size_t)NS * 64) + (t & 1) * 32;
#pragma unroll
      for (int i = 0; i < 2; ++i) {
        const int c = i * 256 + tid;            // 16B-unit index, 0..511
        const int row = c >> 2;
        const int u = c & 3;
        load_lds16(ga + (size_t)row * 64 + u * 8, (char*)As + c * 16);
        load_lds16(gb + (size_t)row * 64 + u * 8, (char*)Bs + c * 16);
      }
    }
    __syncthreads();   // compiler drains vmcnt(0): tile t resident in LDS

    {
      bf16x8 af[4], bf[4];
#pragma unroll
      for (int m = 0; m < 4; ++m)
        af[m] = *(const bf16x8*)&As[(wr + m * 16 + fr) * 32 + fq * 8];
#pragma unroll
      for (int n = 0; n < 4; ++n)
        bf[n] = *(const bf16x8*)&Bs[(wc + n * 16 + fr) * 32 + fq * 8];
#pragma unroll
      for (int m = 0; m < 4; ++m)
#pragma unroll
        for (int n = 0; n < 4; ++n)
          acc[m][n] = __builtin_amdgcn_mfma_f32_16x16x32_bf16(af[m], bf[n], acc[m][n], 0, 0, 0);
    }
    __syncthreads();   // all waves done reading -> safe to overwrite next iter
  }

  if (PASS == 1) {
    const size_t cb = (size_t)(ct * 2 + (wc >> 6));   // output k-block in Hmat_t
#pragma unroll
    for (int n = 0; n < 4; ++n) {
      const int col = ct * 128 + wc + n * 16 + fr;
      const int cl = n * 16 + fr;                     // col within 64-block
      const float b1v = bias[(size_t)e * NS + col];
#pragma unroll
      for (int m = 0; m < 4; ++m) {
#pragma unroll
        for (int r = 0; r < 4; ++r) {
          const int lrow = wr + m * 16 + fq * 4 + r;
          if (lrow < rowsvalid) {
            float v = gelu_f(acc[m][n][r] + b1v);
            Hmat[(cb * NPAD + (gbase + rt * 128 + lrow)) * 64 + cl] = f2bf(v);
          }
        }
      }
    }
  } else {
    float b2v[4];
#pragma unroll
    for (int n = 0; n < 4; ++n)
      b2v[n] = (kz == 0) ? bias[(size_t)e * NS + ct * 128 + wc + n * 16 + fr] : 0.f;
#pragma unroll
    for (int m = 0; m < 4; ++m) {
#pragma unroll
      for (int r = 0; r < 4; ++r) {
        const int lrow = wr + m * 16 + fq * 4 + r;
        if (lrow < rowsvalid) {
          const int g = gbase + rt * 128 + lrow;
          const int ent = pairmap[g];
          const int tok = ent >> 1;
          const float s = score[ent];
#pragma unroll
          for (int n = 0; n < 4; ++n) {
            const int col = ct * 128 + wc + n * 16 + fr;
            atomicAdd(&out[(size_t)tok * DIM + col], s * (acc[m][n][r] + b2v[n]));
          }
        }
      }
    }
  }
}

// ============== fallback: round-1 GEMM (fp32 weights converted in-loop) ==============
template <int PASS>
__global__ __launch_bounds__(256) void moe_gemm(
    const unsigned short* __restrict__ Asrc,
    const float* __restrict__ Bsrc,
    const float* __restrict__ bias,
    const int* __restrict__ offsets,
    const int* __restrict__ pairmap,
    const float* __restrict__ score,
    unsigned short* __restrict__ Hmat,
    float* __restrict__ out) {
  constexpr int K  = (PASS == 1) ? DIM : HID;
  constexpr int NS = (PASS == 1) ? HID : DIM;
  const int e = blockIdx.z;
  const int gbase = offsets[e];
  const int nc = offsets[e + 1] - gbase;
  const int rt = blockIdx.x;
  if (rt * 128 >= nc) return;
  const int rowsvalid = min(128, nc - rt * 128);
  const int ct = blockIdx.y;
  __shared__ unsigned short As[128 * 40];
  __shared__ unsigned short Bs[128 * 40];
  const int tid  = threadIdx.x;
  const int lane = tid & 63;
  const int wid  = tid >> 6;
  const int wr = (wid >> 1) * 64;
  const int wc = (wid & 1) * 64;
  const int fr = lane & 15;
  const int fq = lane >> 4;
  f32x4 acc[4][4];
#pragma unroll
  for (int m = 0; m < 4; ++m)
#pragma unroll
    for (int n = 0; n < 4; ++n) acc[m][n] = (f32x4){0.f, 0.f, 0.f, 0.f};
  const int ar = tid >> 1;
  const int ak = (tid & 1) * 16;
  int arow = rt * 128 + ((ar < rowsvalid) ? ar : 0);
  const unsigned short* Aptr = Asrc + (size_t)(gbase + arow) * K + ak;
  const int bc = (tid & 31) * 4;
  const int bk = (tid >> 5) * 4;
  const float* Bptr = Bsrc + (size_t)e * K * NS + (size_t)bk * NS + ct * 128 + bc;
  for (int k0 = 0; k0 < K; k0 += 32) {
    uint4 av0 = *(const uint4*)(Aptr + k0);
    uint4 av1 = *(const uint4*)(Aptr + k0 + 8);
    const float* bp = Bptr + (size_t)k0 * NS;
    float4 w0 = *(const float4*)(bp);
    float4 w1 = *(const float4*)(bp + NS);
    float4 w2 = *(const float4*)(bp + 2 * NS);
    float4 w3 = *(const float4*)(bp + 3 * NS);
    __syncthreads();
    *(uint4*)&As[ar * 40 + ak]     = av0;
    *(uint4*)&As[ar * 40 + ak + 8] = av1;
    {
      uint2 pv;
      pv.x = (unsigned int)f2bf(w0.x) | ((unsigned int)f2bf(w1.x) << 16);
      pv.y = (unsigned int)f2bf(w2.x) | ((unsigned int)f2bf(w3.x) << 16);
      *(uint2*)&Bs[(bc + 0) * 40 + bk] = pv;
      pv.x = (unsigned int)f2bf(w0.y) | ((unsigned int)f2bf(w1.y) << 16);
      pv.y = (unsigned int)f2bf(w2.y) | ((unsigned int)f2bf(w3.y) << 16);
      *(uint2*)&Bs[(bc + 1) * 40 + bk] = pv;
      pv.x = (unsigned int)f2bf(w0.z) | ((unsigned int)f2bf(w1.z) << 16);
      pv.y = (unsigned int)f2bf(w2.z) | ((unsigned int)f2bf(w3.z) << 16);
      *(uint2*)&Bs[(bc + 2) * 40 + bk] = pv;
      pv.x = (unsigned int)f2bf(w0.w) | ((unsigned int)f2bf(w1.w) << 16);
      pv.y = (unsigned int)f2bf(w2.w) | ((unsigned int)f2bf(w3.w) << 16);
      *(uint2*)&Bs[(bc + 3) * 40 + bk] = pv;
    }
    __syncthreads();
    bf16x8 af[4], bfr[4];
#pragma unroll
    for (int m = 0; m < 4; ++m)
      af[m] = *(const bf16x8*)&As[(wr + m * 16 + fr) * 40 + fq * 8];
#pragma unroll
    for (int n = 0; n < 4; ++n)
      bfr[n] = *(const bf16x8*)&Bs[(wc + n * 16 + fr) * 40 + fq * 8];
#pragma unroll
    for (int m = 0; m < 4; ++m)
#pragma unroll
      for (int n = 0; n < 4; ++n)
        acc[m][n] = __builtin_amdgcn_mfma_f32_16x16x32_bf16(af[m], bfr[n], acc[m][n], 0, 0, 0);
  }
  if (PASS == 1) {
#pragma unroll
    for (int n = 0; n < 4; ++n) {
      int col = ct * 128 + wc + n * 16 + fr;
      float b1v = bias[(size_t)e * NS + col];
#pragma unroll
      for (int m = 0; m < 4; ++m) {
#pragma unroll
        for (int r = 0; r < 4; ++r) {
          int lrow = wr + m * 16 + fq * 4 + r;
          if (lrow < rowsvalid) {
            float v = acc[m][n][r] + b1v;
            v = 0.5f * v * (1.f + erff(v * 0.70710678118654752440f));
            Hmat[(size_t)(gbase + rt * 128 + lrow) * HID + col] = f2bf(v);
          }
        }
      }
    }
  } else {
    float b2v[4];
#pragma unroll
    for (int n = 0; n < 4; ++n)
      b2v[n] = bias[(size_t)e * NS + ct * 128 + wc + n * 16 + fr];
#pragma unroll
    for (int m = 0; m < 4; ++m) {
#pragma unroll
      for (int r = 0; r < 4; ++r) {
        int lrow = wr + m * 16 + fq * 4 + r;
        if (lrow < rowsvalid) {
          int g = gbase + rt * 128 + lrow;
          int ent = pairmap[g];
          int tok = ent >> 1;
          float s = score[ent];
#pragma unroll
          for (int n = 0; n < 4; ++n) {
            int col = ct * 128 + wc + n * 16 + fr;
            atomicAdd(&out[(size_t)tok * DIM + col], s * (acc[m][n][r] + b2v[n]));
          }
        }
      }
    }
  }
}

extern "C" void kernel_launch(void* const* d_in, const int* in_sizes, int n_in,
                              void* d_out, int out_size, void* d_ws, size_t ws_size,
                              hipStream_t stream) {
  const float* x  = (const float*)d_in[0];
  const float* W1 = (const float*)d_in[1];
  const float* b1 = (const float*)d_in[2];
  const float* W2 = (const float*)d_in[3];
  const float* b2 = (const float*)d_in[4];
  const float* Wg = (const float*)d_in[5];
  const float* bg = (const float*)d_in[6];
  float* out = (float*)d_out;
  const int N  = in_sizes[0] / DIM;   // tokens (4096)
  const int NP = N * TOPK;            // pairs (8192)
  const int NPAD = NP + 256;          // padded row space (staging over-read)
  const int MAXT = NP / 128 + NEXP;   // worst-case 128-row tiles (72)

  char* ws = (char*)d_ws;
  size_t off = 0;
  auto alloc = [&](size_t bytes) -> void* {
    void* p = ws + off;
    off = (off + bytes + 255) & ~(size_t)255;
    return p;
  };
  int*   count      = (int*)alloc(NEXP * sizeof(int));
  int*   offsets    = (int*)alloc((NEXP + 1) * sizeof(int));
  int*   tiles      = (int*)alloc((size_t)MAXT * sizeof(int));
  int*   ntiles     = (int*)alloc(sizeof(int));
  float* topk_score = (float*)alloc((size_t)NP * sizeof(float));
  int*   lists      = (int*)alloc((size_t)NEXP * N * sizeof(int));
  int*   pairmap    = (int*)alloc((size_t)NP * sizeof(int));
  // K-tiled: Xg [16][NPAD][64], Hmat [64][NPAD][64]
  unsigned short* Xg   = (unsigned short*)alloc((size_t)NPAD * DIM * sizeof(unsigned short));
  unsigned short* Hmat = (unsigned short*)alloc((size_t)NPAD * HID * sizeof(unsigned short));
  unsigned short* W1T = (unsigned short*)alloc((size_t)NEXP * DIM * HID * sizeof(unsigned short));
  unsigned short* W2T = (unsigned short*)alloc((size_t)NEXP * HID * DIM * sizeof(unsigned short));
  size_t need_full = off;

  hipMemsetAsync(count, 0, NEXP * sizeof(int), stream);
  gate_kernel<<<(N + 3) / 4, 256, 0, stream>>>(x, Wg, bg, topk_score, count, lists, N);
  offsets_kernel<<<1, 64, 0, stream>>>(count, offsets, tiles, ntiles);
  hipMemsetAsync(out, 0, (size_t)out_size * sizeof(float), stream);

  if (ws_size >= need_full) {
    gather_kernel<1><<<NP, DIM / 4, 0, stream>>>(x, offsets, lists, Xg, pairmap, N, NPAD);
    // one-time weight transpose-convert to bf16 K-tiled, single merged launch
    transpose_convert_all<<<4096, 256, 0, stream>>>(W1, W2, W1T, W2T);

    dim3 g1((HID / 128) * MAXT, 1, 1);   // 1D, tile-fastest + XCD chunk swizzle
    moe_gemm14<1><<<g1, 256, 0, stream>>>(Xg, W1T, b1, offsets, tiles, ntiles,
                                          pairmap, topk_score, Hmat, out, MAXT, NPAD);
    dim3 g2((DIM / 128) * MAXT, 1, 2);   // kz=2
    moe_gemm14<2><<<g2, 256, 0, stream>>>(Hmat, W2T, b2, offsets, tiles, ntiles,
                                          pairmap, topk_score, Hmat, out, MAXT, NPAD);
  } else {
    gather_kernel<0><<<NP, DIM / 4, 0, stream>>>(x, offsets, lists, Xg, pairmap, N, NPAD);
    const int RT = (N + 127) / 128;
    dim3 g1(RT, HID / 128, NEXP);
    moe_gemm<1><<<g1, 256, 0, stream>>>(Xg, W1, b1, offsets, pairmap, topk_score, Hmat, out);
    dim3 g2(RT, DIM / 128, NEXP);
    moe_gemm<2><<<g2, 256, 0, stream>>>(Hmat, W2, b2, offsets, pairmap, topk_score, Hmat, out);
  }
}